// Round 5
// baseline (353.634 us; speedup 1.0000x reference)
//
#include <hip/hip_runtime.h>
#include <hip/hip_bf16.h>
#include <math.h>

// x(32,512,768) fp32 -> LayerNorm(768) -> Linear 768x3072 + bias -> exact GELU
// M = 16384, K = 768, N = 3072. Output fp32.
#define M_ROWS 16384
#define K_DIM  768
#define N_DIM  3072
#define NT     12      // K_DIM / 64 K-tiles

typedef __bf16 bf16x8 __attribute__((ext_vector_type(8)));
typedef float  f32x4  __attribute__((ext_vector_type(4)));
typedef unsigned short u16x4 __attribute__((ext_vector_type(4)));

__device__ __forceinline__ unsigned short f2bf(float f) {
    unsigned int u = __float_as_uint(f);
    unsigned int r = (u + 0x7fffu + ((u >> 16) & 1u)) >> 16;   // RNE
    return (unsigned short)r;
}

__device__ __forceinline__ void async16(const unsigned short* g, unsigned short* l) {
    __builtin_amdgcn_global_load_lds(
        (const __attribute__((address_space(1))) unsigned int*)g,
        (__attribute__((address_space(3))) unsigned int*)l,
        16, 0, 0);
}

// tanh-form GELU: 0.5h(1+tanh(0.79788456(h+0.044715h^3))); max |err| vs erf ~1e-3
__device__ __forceinline__ float gelu_fast(float h) {
    float h2 = h * h;
    float z2 = h * __builtin_fmaf(0.0713548162f, h2, 1.5957691216f); // 2*z
    float E  = __expf(z2);                                           // e^{2z}
    float r  = __builtin_amdgcn_rcpf(1.0f + E);                      // (1-tanh)/2
    return h - h * r;                                                // 0.5h(1+tanh)
}

// ---------- 1) LayerNorm + cast to bf16 (vectorized) ----------
__global__ __launch_bounds__(256) void ln_kernel(const float* __restrict__ x,
                                                 const float* __restrict__ gamma,
                                                 const float* __restrict__ beta,
                                                 unsigned short* __restrict__ xn) {
    int wave = threadIdx.x >> 6;
    int lane = threadIdx.x & 63;
    int row  = blockIdx.x * 4 + wave;
    const f32x4* xr = (const f32x4*)(x + (size_t)row * K_DIM);
    const f32x4* g4 = (const f32x4*)gamma;
    const f32x4* b4 = (const f32x4*)beta;

    f32x4 v[3];
    float s = 0.f, ss = 0.f;
#pragma unroll
    for (int q = 0; q < 3; q++) {
        v[q] = __builtin_nontemporal_load(&xr[lane + 64 * q]);   // x read exactly once
#pragma unroll
        for (int e = 0; e < 4; e++) { s += v[q][e]; ss += v[q][e] * v[q][e]; }
    }
#pragma unroll
    for (int off = 32; off; off >>= 1) {
        s  += __shfl_xor(s,  off, 64);
        ss += __shfl_xor(ss, off, 64);
    }
    float mu   = s * (1.f / K_DIM);
    float var  = ss * (1.f / K_DIM) - mu * mu;
    float rstd = rsqrtf(var + 1e-12f);

    u16x4* xo = (u16x4*)(xn + (size_t)row * K_DIM);
#pragma unroll
    for (int q = 0; q < 3; q++) {
        f32x4 gv = g4[lane + 64 * q];
        f32x4 bv = b4[lane + 64 * q];
        u16x4 o;
#pragma unroll
        for (int e = 0; e < 4; e++)
            o[e] = f2bf((v[q][e] - mu) * rstd * gv[e] + bv[e]);
        xo[lane + 64 * q] = o;
    }
}

// ---------- 2) W [K,N] fp32 -> Wt [N,K] bf16 ----------
__global__ __launch_bounds__(256) void wcast_kernel(const float* __restrict__ W,
                                                    unsigned short* __restrict__ wt) {
    __shared__ float tile[32][33];
    int bx = blockIdx.x, by = blockIdx.y;
    int tx = threadIdx.x, ty = threadIdx.y;
#pragma unroll
    for (int r = 0; r < 4; r++)
        tile[ty + 8 * r][tx] = __builtin_nontemporal_load(
            &W[(size_t)(by * 32 + ty + 8 * r) * N_DIM + bx * 32 + tx]);  // W read once
    __syncthreads();
#pragma unroll
    for (int r = 0; r < 4; r++)
        wt[(size_t)(bx * 32 + ty + 8 * r) * K_DIM + by * 32 + tx] = f2bf(tile[tx][ty + 8 * r]);
}

// ---------- 3) GEMM + bias + GELU: 256x256, BK=64, 8 waves, 1-sync/tile pipeline ----------
// HARDENED round-3 experiment: same software-pipelined structure (full-tile
// double buffer; staging only ever writes the buffer NOT being read; 4
// register-staggered quadrant phases per tile; ONE boundary per tile instead
// of 8 barriers) but ALL hand-written s_waitcnt/s_barrier protocol replaced by
// __syncthreads(), whose compiler-emitted vmcnt(0)+lgkmcnt(0)+s_barrier is
// exactly the boundary invariant needed:
//   - vmcnt(0):   tile t+1 staging resident in nb before anyone reads it
//   - lgkmcnt(0): this wave's LDS reads of bf complete before the barrier, so
//                 staging into bf at tile t+1 (issued only after the barrier)
//                 cannot overwrite live data.
// Rep-tail staging into buf0 needs NO extra barrier: buf0's last reads drained
// at the t=NT-2 boundary, which every wave passed before reaching the tail.
__global__ __launch_bounds__(512, 2) void gemm_kernel(const unsigned short* __restrict__ A,
                                                      const unsigned short* __restrict__ B,
                                                      const float* __restrict__ bias,
                                                      float* __restrict__ C) {
    __shared__ __attribute__((aligned(16))) unsigned short As[2][256 * 64];
    __shared__ __attribute__((aligned(16))) unsigned short Bs[2][256 * 64];

    int tid   = threadIdx.x;
    int lane  = tid & 63;
    int wid   = tid >> 6;
    int waveM = wid >> 2;        // 0..1 -> 128 M-rows each
    int waveN = wid & 3;         // 0..3 -> 64 N-cols each

    // 256 blocks, 8 XCDs: XCD k gets wg [32k,32k+32) = contiguous bm panels,
    // 2 XCDs share one bng (3 B panels, ~1.2 MB, L2-resident).
    int orig = blockIdx.y * 4 + blockIdx.x;
    int wg   = (orig & 7) * 32 + (orig >> 3);
    int bng  = wg >> 6;          // 0..3 -> bn = bng*3 + rep
    int bm   = wg & 63;

    const unsigned short* Ag = A + (size_t)bm * 256 * K_DIM;
    const unsigned short* Bg = B + (size_t)(bng * 3) * 256 * K_DIM;

    // staging geometry: per unit, thread covers (row_in_unit = l*64 + rsub, chunk = cch)
    int rsub = wid * 8 + (lane >> 3);   // 0..63, wave-contiguous 8-row span
    int cch  = lane & 7;
    int sch  = cch ^ (rsub & 7);        // pre-swizzled source chunk (row&7 == rsub&7)

    int mrow = lane & 15;
    int quad = lane >> 4;
    int swz  = mrow & 7;

    f32x4 acc[4][8];

#define STAGE_A(gp, a, kt, bfi) do { \
        _Pragma("unroll") \
        for (int l = 0; l < 2; ++l) { \
            int pr = l * 128 + (a) * 64 + rsub; \
            async16((gp) + (size_t)pr * K_DIM + (kt) * 64 + sch * 8, \
                    &As[bfi][pr * 64 + cch * 8]); \
        } } while (0)
#define STAGE_B(gp, b, kt, bfi) do { \
        _Pragma("unroll") \
        for (int l = 0; l < 2; ++l) { \
            int pr = l * 128 + (b) * 32 + (rsub & 31) + ((rsub >> 5) << 6); \
            async16((gp) + (size_t)pr * K_DIM + (kt) * 64 + sch * 8, \
                    &Bs[bfi][pr * 64 + cch * 8]); \
        } } while (0)

#define RD_X(j, kk, bfi) (*(const bf16x8*)&As[bfi][(waveM * 128 + (j) * 16 + mrow) * 64 + ((((kk) * 4 + quad) ^ swz) * 8)])
#define RD_W(i, kk, bfi) (*(const bf16x8*)&Bs[bfi][(waveN * 64  + (i) * 16 + mrow) * 64 + ((((kk) * 4 + quad) ^ swz) * 8)])

    // MFMA quadrant: acc[I0..I0+1][J0..J0+3] += WF x XF  (16 MFMA, setprio-wrapped)
#define MFMA_Q(I0, J0, WF, XF) do { \
        __builtin_amdgcn_s_setprio(1); \
        _Pragma("unroll") \
        for (int jj = 0; jj < 4; ++jj) { \
            _Pragma("unroll") \
            for (int kk = 0; kk < 2; ++kk) { \
                acc[(I0)][(J0) + jj]     = __builtin_amdgcn_mfma_f32_16x16x32_bf16(WF[0][kk], XF[jj][kk], acc[(I0)][(J0) + jj], 0, 0, 0); \
                acc[(I0) + 1][(J0) + jj] = __builtin_amdgcn_mfma_f32_16x16x32_bf16(WF[1][kk], XF[jj][kk], acc[(I0) + 1][(J0) + jj], 0, 0, 0); \
            } \
        } \
        __builtin_amdgcn_s_setprio(0); \
    } while (0)

    bf16x8 xfA[4][2], xfB[4][2], wfA[2][2], wfB[2][2], wfA2[2][2];

    // rep-0 prologue: stage tile0 -> buf0, full drain, pre-read xfA(tile0)
    STAGE_A(Ag, 0, 0, 0); STAGE_A(Ag, 1, 0, 0); STAGE_B(Bg, 0, 0, 0); STAGE_B(Bg, 1, 0, 0);
    __syncthreads();
#pragma unroll
    for (int j = 0; j < 4; ++j) { xfA[j][0] = RD_X(j, 0, 0); xfA[j][1] = RD_X(j, 1, 0); }

    for (int rep = 0; rep < 3; ++rep) {
#pragma unroll
        for (int i = 0; i < 4; ++i)
#pragma unroll
            for (int j = 0; j < 8; ++j)
                acc[i][j] = (f32x4){0.f, 0.f, 0.f, 0.f};

        for (int t = 0; t < NT; ++t) {
            int bf = t & 1, nb = bf ^ 1;
            int more = (t + 1 < NT);

            // PhA: wfA(t) reads; stage A(t+1)->nb; MFMA Q0 {wfA, xfA}
            wfA[0][0] = RD_W(0, 0, bf); wfA[0][1] = RD_W(0, 1, bf);
            wfA[1][0] = RD_W(1, 0, bf); wfA[1][1] = RD_W(1, 1, bf);
            if (more) { STAGE_A(Ag, 0, t + 1, nb); STAGE_A(Ag, 1, t + 1, nb); }
            MFMA_Q(0, 0, wfA, xfA);

            // PhB: wfB reads; stage B(t+1)->nb; MFMA Q1 {wfB, xfA}
            wfB[0][0] = RD_W(2, 0, bf); wfB[0][1] = RD_W(2, 1, bf);
            wfB[1][0] = RD_W(3, 0, bf); wfB[1][1] = RD_W(3, 1, bf);
            if (more) { STAGE_B(Bg, 0, t + 1, nb); STAGE_B(Bg, 1, t + 1, nb); }
            MFMA_Q(2, 0, wfB, xfA);

            // PhC: xfB + wfA2 reads (all remaining bf reads); MFMA Q2 {wfB, xfB}
#pragma unroll
            for (int j = 0; j < 4; ++j) { xfB[j][0] = RD_X(j + 4, 0, bf); xfB[j][1] = RD_X(j + 4, 1, bf); }
            wfA2[0][0] = RD_W(0, 0, bf); wfA2[0][1] = RD_W(0, 1, bf);
            wfA2[1][0] = RD_W(1, 0, bf); wfA2[1][1] = RD_W(1, 1, bf);
            MFMA_Q(2, 4, wfB, xfB);

            // PhD: single tile boundary (__syncthreads = vmcnt0+lgkmcnt0+barrier),
            // then pre-read xfA(t+1) from nb (hidden under Q3's pipe drain),
            // then Q3 {wfA2, xfB} on registers.
            if (more) {
                __syncthreads();
#pragma unroll
                for (int j = 0; j < 4; ++j) { xfA[j][0] = RD_X(j, 0, nb); xfA[j][1] = RD_X(j, 1, nb); }
            }
            MFMA_Q(0, 4, wfA2, xfB);
        }

        int bn = bng * 3 + rep;
        int m0 = bm * 256 + waveM * 128 + mrow;
        int n0 = bn * 256 + waveN * 64 + quad * 4;
        const unsigned short* Bg2 = B + (size_t)(bn + 1) * 256 * K_DIM;

        // rep tail: stage next rep's tile0 into buf0 BEFORE the epilogue so the
        // GELU+store work hides the load latency. Race-free without a barrier:
        // all waves' buf0 reads drained at the t=NT-2 __syncthreads boundary.
        if (rep < 2) {
            STAGE_A(Ag, 0, 0, 0); STAGE_A(Ag, 1, 0, 0);
            STAGE_B(Bg2, 0, 0, 0); STAGE_B(Bg2, 1, 0, 0);
        }

        // epilogue: bias + GELU + nontemporal store (C written once, never read)
#pragma unroll
        for (int i = 0; i < 4; ++i) {
            f32x4 bb = *(const f32x4*)(bias + n0 + i * 16);
#pragma unroll
            for (int j = 0; j < 8; ++j) {
                f32x4 o;
#pragma unroll
                for (int r = 0; r < 4; ++r)
                    o[r] = gelu_fast(acc[i][j][r] + bb[r]);
                __builtin_nontemporal_store(o, (f32x4*)(C + (size_t)(m0 + j * 16) * N_DIM + n0 + i * 16));
            }
        }

        if (rep < 2) {
            __syncthreads();   // drain tile0 staging (+stores) before reading buf0
#pragma unroll
            for (int j = 0; j < 4; ++j) { xfA[j][0] = RD_X(j, 0, 0); xfA[j][1] = RD_X(j, 1, 0); }
            Bg = Bg2;
        }
    }
}

extern "C" void kernel_launch(void* const* d_in, const int* in_sizes, int n_in,
                              void* d_out, int out_size, void* d_ws, size_t ws_size,
                              hipStream_t stream) {
    const float* x     = (const float*)d_in[0];
    const float* gamma = (const float*)d_in[1];
    const float* beta  = (const float*)d_in[2];
    const float* W     = (const float*)d_in[3];
    const float* bias  = (const float*)d_in[4];
    float* out = (float*)d_out;

    unsigned short* xn = (unsigned short*)d_ws;
    unsigned short* wt = xn + (size_t)M_ROWS * K_DIM;

    ln_kernel<<<M_ROWS / 4, 256, 0, stream>>>(x, gamma, beta, xn);
    wcast_kernel<<<dim3(N_DIM / 32, K_DIM / 32), dim3(32, 8), 0, stream>>>(W, wt);
    gemm_kernel<<<dim3(4, 64), 512, 0, stream>>>(xn, wt, bias, out);
}